// Round 3
// baseline (4486.916 us; speedup 1.0000x reference)
//
#include <hip/hip_runtime.h>
#include <hip/hip_bf16.h>

// DecoderLSTM: B=64, U=1024, V=E=8000, T=64.
// Strategy: pre-transpose+convert all weights to bf16 [N][K] once per launch,
// then per step run bf16 MFMA GEMMs (fragment-direct, no LDS) with K-split
// partials, fused cell update, and per-row softmax. Memory-bound on weight
// streaming (90 MB bf16 / step, L3-resident after step 1).

typedef short  s16x8 __attribute__((ext_vector_type(8)));
typedef float  f32x4 __attribute__((ext_vector_type(4)));

constexpr int B_ = 64;
constexpr int U_ = 1024;
constexpr int E_ = 8000;
constexpr int V_ = 8000;
constexpr int T_ = 64;

constexpr int XCHUNKS = E_ / 32;              // 250
constexpr int HCHUNKS = U_ / 32;              // 32
constexpr int TCHUNKS = XCHUNKS + HCHUNKS;    // 282
constexpr int KSG = 8;                        // K-split for gates GEMM -> 512 blocks
constexpr int KSP = 4;                        // K-split for proj GEMM  -> 500 blocks
constexpr int PCH = U_ / 32;                  // 32 chunks in proj K
constexpr int SMT = 1024;                     // softmax threads/block

#define DEVINL static __device__ __forceinline__

DEVINL short f2bf(float x) {
  unsigned u = __builtin_bit_cast(unsigned, x);
  unsigned r = (u + 0x7fffu + ((u >> 16) & 1u)) >> 16;   // RNE
  return (short)r;
}
DEVINL float sigm(float x) { return 1.f / (1.f + __expf(-x)); }
DEVINL int imin(int a, int b) { return a < b ? a : b; }
DEVINL int imax(int a, int b) { return a > b ? a : b; }

// ---------------- one-time weight transpose + f32->bf16 convert ----------------
// out[c][r] = bf16(in[r][c]);  R, C multiples of 64.
__global__ __launch_bounds__(256) void k_transpose(const float* __restrict__ in,
                                                   short* __restrict__ out,
                                                   int R, int C) {
  __shared__ float tile[64][65];
  int r0 = blockIdx.x * 64, c0 = blockIdx.y * 64;
  int tx = threadIdx.x & 63, ty = threadIdx.x >> 6;
#pragma unroll
  for (int i = 0; i < 16; ++i) {
    int rl = ty * 16 + i;
    tile[rl][tx] = in[(size_t)(r0 + rl) * C + (c0 + tx)];
  }
  __syncthreads();
#pragma unroll
  for (int i = 0; i < 16; ++i) {
    int cl = ty * 16 + i;
    out[(size_t)(c0 + cl) * R + (r0 + tx)] = f2bf(tile[tx][cl]);
  }
}

__global__ __launch_bounds__(256) void k_f2bf_vec(const float* __restrict__ in,
                                                  short* __restrict__ out, int n) {
  int i = blockIdx.x * 256 + threadIdx.x;
  if (i < n) out[i] = f2bf(in[i]);
}

// ---------------- gates GEMM: preact[b, g*U+u] partials ----------------
// A = out_{t-1} (B x E bf16), H = h_{t-1} (B x U bf16)
// WxT: 4 x [U][E] bf16, WhT: 4 x [U][U] bf16
// part: [KSG][B][4U] f32
__global__ __launch_bounds__(256) void k_gates(const short* __restrict__ Abuf,
                                               const short* __restrict__ Hbuf,
                                               const short* __restrict__ WxT,
                                               const short* __restrict__ WhT,
                                               float* __restrict__ part, int t) {
  int gx = blockIdx.x;           // u-tile of 64: 0..15
  int gate = blockIdx.y;         // 0..3 (f,i,o,g)
  int z = blockIdx.z;            // 0..KSG-1
  int wave = threadIdx.x >> 6;
  int lane = threadIdx.x & 63;
  int l15 = lane & 15, lg = lane >> 4;

  int ucol = gx * 64 + wave * 16 + l15;
  const short* wx = WxT + ((size_t)gate * U_ + ucol) * E_;
  const short* wh = WhT + ((size_t)gate * U_ + ucol) * U_;

  int c0 = (TCHUNKS * z) / KSG, c1 = (TCHUNKS * (z + 1)) / KSG;

  f32x4 zero = {};
  f32x4 acc[4];
#pragma unroll
  for (int r = 0; r < 4; ++r) acc[r] = zero;

  int xe = imin(c1, XCHUNKS);
#pragma unroll 2
  for (int c = c0; c < xe; ++c) {
    int k = c * 32 + lg * 8;
    s16x8 b = *(const s16x8*)(wx + k);
#pragma unroll
    for (int r = 0; r < 4; ++r) {
      s16x8 a = *(const s16x8*)(Abuf + (size_t)(r * 16 + l15) * E_ + k);
      acc[r] = __builtin_amdgcn_mfma_f32_16x16x32_bf16(a, b, acc[r], 0, 0, 0);
    }
  }
  if (t > 0) {
    int h0 = imax(c0, XCHUNKS);
#pragma unroll 2
    for (int c = h0; c < c1; ++c) {
      int k = (c - XCHUNKS) * 32 + lg * 8;
      s16x8 b = *(const s16x8*)(wh + k);
#pragma unroll
      for (int r = 0; r < 4; ++r) {
        s16x8 a = *(const s16x8*)(Hbuf + (size_t)(r * 16 + l15) * U_ + k);
        acc[r] = __builtin_amdgcn_mfma_f32_16x16x32_bf16(a, b, acc[r], 0, 0, 0);
      }
    }
  }
  float* p = part + (size_t)z * B_ * (4 * U_) + (size_t)gate * U_ + gx * 64 + wave * 16 + l15;
#pragma unroll
  for (int r = 0; r < 4; ++r)
#pragma unroll
    for (int j = 0; j < 4; ++j) {
      int row = r * 16 + lg * 4 + j;
      p[(size_t)row * (4 * U_)] = acc[r][j];
    }
}

// ---------------- cell update: sigmoid(preact) -> c,h ----------------
__global__ __launch_bounds__(256) void k_cell(const float* __restrict__ part,
                                              const float* __restrict__ bfv,
                                              const float* __restrict__ biv,
                                              const float* __restrict__ bov,
                                              const float* __restrict__ bgv,
                                              float* __restrict__ cbuf,
                                              short* __restrict__ Hbuf, int t) {
  int idx = blockIdx.x * 256 + threadIdx.x;   // 0 .. B*U-1
  int u = idx & (U_ - 1);
  int b = idx >> 10;
  float pf = bfv[u], pi = biv[u], po = bov[u], pg = bgv[u];
#pragma unroll
  for (int z = 0; z < KSG; ++z) {
    const float* pz = part + ((size_t)z * B_ + b) * (4 * U_) + u;
    pf += pz[0];
    pi += pz[U_];
    po += pz[2 * U_];
    pg += pz[3 * U_];
  }
  float f = sigm(pf), i = sigm(pi), o = sigm(po), g = sigm(pg);
  float cold = (t == 0) ? 0.f : cbuf[idx];
  float cn = f * cold + i * g;
  cbuf[idx] = cn;
  float h = tanhf(cn) * o;
  Hbuf[idx] = f2bf(h);
}

// ---------------- projection GEMM: logits partials ----------------
// H: B x U bf16, WpT: [V][U] bf16, part: [KSP][B][V] f32
__global__ __launch_bounds__(256) void k_proj(const short* __restrict__ Hbuf,
                                              const short* __restrict__ WpT,
                                              float* __restrict__ part) {
  int gx = blockIdx.x;           // v-tile of 64: 0..124
  int z = blockIdx.y;            // 0..KSP-1
  int wave = threadIdx.x >> 6;
  int lane = threadIdx.x & 63;
  int l15 = lane & 15, lg = lane >> 4;
  int vcol = gx * 64 + wave * 16 + l15;
  const short* wp = WpT + (size_t)vcol * U_;
  int c0 = (PCH * z) / KSP, c1 = (PCH * (z + 1)) / KSP;

  f32x4 zero = {};
  f32x4 acc[4];
#pragma unroll
  for (int r = 0; r < 4; ++r) acc[r] = zero;

#pragma unroll 2
  for (int c = c0; c < c1; ++c) {
    int k = c * 32 + lg * 8;
    s16x8 b = *(const s16x8*)(wp + k);
#pragma unroll
    for (int r = 0; r < 4; ++r) {
      s16x8 a = *(const s16x8*)(Hbuf + (size_t)(r * 16 + l15) * U_ + k);
      acc[r] = __builtin_amdgcn_mfma_f32_16x16x32_bf16(a, b, acc[r], 0, 0, 0);
    }
  }
  float* p = part + (size_t)z * B_ * V_ + vcol;
#pragma unroll
  for (int r = 0; r < 4; ++r)
#pragma unroll
    for (int j = 0; j < 4; ++j) {
      int row = r * 16 + lg * 4 + j;
      p[(size_t)row * V_] = acc[r][j];
    }
}

// ---------------- softmax + output write + bf16 feedback ----------------
// 1024 threads/block: 16 waves streaming 128KB partials + 96KB stores per row.
__global__ __launch_bounds__(SMT) void k_softmax(const float* __restrict__ part,
                                                 const float* __restrict__ bp,
                                                 float* __restrict__ dout,
                                                 short* __restrict__ Abuf, int t) {
  __shared__ float row[V_];
  __shared__ float red[SMT / 64 + 1];
  constexpr int NW = SMT / 64;
  int b = blockIdx.x;
  int tid = threadIdx.x, lane = tid & 63, wave = tid >> 6;

  float lmax = -3.4e38f;
  for (int v = tid; v < V_; v += SMT) {
    float x = bp[v];
#pragma unroll
    for (int z = 0; z < KSP; ++z) x += part[((size_t)z * B_ + b) * V_ + v];
    row[v] = x;
    lmax = fmaxf(lmax, x);
  }
#pragma unroll
  for (int off = 32; off; off >>= 1) lmax = fmaxf(lmax, __shfl_down(lmax, off));
  if (lane == 0) red[wave] = lmax;
  __syncthreads();
  if (tid == 0) {
    float m = red[0];
    for (int w = 1; w < NW; ++w) m = fmaxf(m, red[w]);
    red[NW] = m;
  }
  __syncthreads();
  float gmax = red[NW];
  float lsum = 0.f;
  for (int v = tid; v < V_; v += SMT) {
    float e = __expf(row[v] - gmax);
    row[v] = e;
    lsum += e;
  }
#pragma unroll
  for (int off = 32; off; off >>= 1) lsum += __shfl_down(lsum, off);
  if (lane == 0) red[wave] = lsum;
  __syncthreads();
  if (tid == 0) {
    float s = 0.f;
    for (int w = 0; w < NW; ++w) s += red[w];
    red[NW] = s;
  }
  __syncthreads();
  float inv = 1.f / red[NW];
  float* po = dout + ((size_t)b * T_ + t) * V_;
  short* pa = Abuf + (size_t)b * V_;
  for (int v = tid; v < V_; v += SMT) {
    float pr = row[v] * inv;
    po[v] = pr;
    pa[v] = f2bf(pr);
  }
}

extern "C" void kernel_launch(void* const* d_in, const int* in_sizes, int n_in,
                              void* d_out, int out_size, void* d_ws, size_t ws_size,
                              hipStream_t stream) {
  const float* y = (const float*)d_in[0];
  const float* Wx[4] = {(const float*)d_in[1], (const float*)d_in[4],
                        (const float*)d_in[7], (const float*)d_in[10]};
  const float* Wh[4] = {(const float*)d_in[2], (const float*)d_in[5],
                        (const float*)d_in[8], (const float*)d_in[11]};
  const float* bs[4] = {(const float*)d_in[3], (const float*)d_in[6],
                        (const float*)d_in[9], (const float*)d_in[12]};
  const float* Wp = (const float*)d_in[13];
  const float* bp = (const float*)d_in[14];
  float* dout = (float*)d_out;

  // workspace layout (all 256B aligned); total ~109 MB
  char* w = (char*)d_ws;
  auto alloc = [&](size_t bytes) {
    char* p = w;
    w += (bytes + 255) & ~(size_t)255;
    return p;
  };
  short* WxT  = (short*)alloc((size_t)4 * U_ * E_ * 2);     // 65.5 MB
  short* WhT  = (short*)alloc((size_t)4 * U_ * U_ * 2);     // 8.4 MB
  short* WpT  = (short*)alloc((size_t)V_ * U_ * 2);         // 16.4 MB
  short* Abuf = (short*)alloc((size_t)B_ * V_ * 2);         // 1.0 MB
  short* Hbuf = (short*)alloc((size_t)B_ * U_ * 2);         // 0.13 MB
  float* cbuf = (float*)alloc((size_t)B_ * U_ * 4);         // 0.26 MB
  float* partg = (float*)alloc((size_t)KSG * B_ * 4 * U_ * 4); // 8.4 MB
  float* partp = (float*)alloc((size_t)KSP * B_ * V_ * 4);     // 8.2 MB
  (void)in_sizes; (void)n_in; (void)out_size; (void)ws_size;

  // one-time per launch: transpose + convert weights to bf16 [N][K]
  for (int g = 0; g < 4; ++g) {
    k_transpose<<<dim3(E_ / 64, U_ / 64), 256, 0, stream>>>(
        Wx[g], WxT + (size_t)g * U_ * E_, E_, U_);
    k_transpose<<<dim3(U_ / 64, U_ / 64), 256, 0, stream>>>(
        Wh[g], WhT + (size_t)g * U_ * U_, U_, U_);
  }
  k_transpose<<<dim3(U_ / 64, V_ / 64), 256, 0, stream>>>(Wp, WpT, U_, V_);
  k_f2bf_vec<<<dim3((B_ * E_ + 255) / 256), 256, 0, stream>>>(y, Abuf, B_ * E_);

  for (int t = 0; t < T_; ++t) {
    k_gates<<<dim3(16, 4, KSG), 256, 0, stream>>>(Abuf, Hbuf, WxT, WhT, partg, t);
    k_cell<<<dim3(B_ * U_ / 256), 256, 0, stream>>>(partg, bs[0], bs[1], bs[2],
                                                    bs[3], cbuf, Hbuf, t);
    k_proj<<<dim3(V_ / 64, KSP), 256, 0, stream>>>(Hbuf, WpT, partp);
    k_softmax<<<dim3(B_), SMT, 0, stream>>>(partp, bp, dout, Abuf, t);
  }
}

// Round 4
// 3399.541 us; speedup vs baseline: 1.3199x; 1.3199x over previous
//
#include <hip/hip_runtime.h>
#include <hip/hip_bf16.h>

// DecoderLSTM: B=64, U=1024, V=E=8000, T=64.
// bf16 MFMA GEMMs, weights pre-transposed to [N][K] once per launch.
// R3: 4-gate-fused k_gates (A-frags loaded once, 8 loads/16 MFMAs),
// vectorized cell+softmax, partg/partp aliased.

typedef short  s16x8 __attribute__((ext_vector_type(8)));
typedef short  s16x4 __attribute__((ext_vector_type(4)));
typedef float  f32x4 __attribute__((ext_vector_type(4)));

constexpr int B_ = 64;
constexpr int U_ = 1024;
constexpr int E_ = 8000;
constexpr int V_ = 8000;
constexpr int T_ = 64;

constexpr int XCHUNKS = E_ / 32;              // 250
constexpr int HCHUNKS = U_ / 32;              // 32
constexpr int TCHUNKS = XCHUNKS + HCHUNKS;    // 282
constexpr int KSG = 16;                       // K-split for gates -> 32x16=512 blocks
constexpr int KSP = 4;                        // K-split for proj  -> 500 blocks
constexpr int PCH = U_ / 32;                  // 32 chunks in proj K
constexpr int SMT = 1024;                     // softmax threads/block

#define DEVINL static __device__ __forceinline__

DEVINL short f2bf(float x) {
  unsigned u = __builtin_bit_cast(unsigned, x);
  unsigned r = (u + 0x7fffu + ((u >> 16) & 1u)) >> 16;   // RNE
  return (short)r;
}
DEVINL float sigm(float x) { return 1.f / (1.f + __expf(-x)); }
DEVINL int imin(int a, int b) { return a < b ? a : b; }
DEVINL int imax(int a, int b) { return a > b ? a : b; }

// ---------------- one-time weight transpose + f32->bf16 convert ----------------
__global__ __launch_bounds__(256) void k_transpose(const float* __restrict__ in,
                                                   short* __restrict__ out,
                                                   int R, int C) {
  __shared__ float tile[64][65];
  int r0 = blockIdx.x * 64, c0 = blockIdx.y * 64;
  int tx = threadIdx.x & 63, ty = threadIdx.x >> 6;
#pragma unroll
  for (int i = 0; i < 16; ++i) {
    int rl = ty * 16 + i;
    tile[rl][tx] = in[(size_t)(r0 + rl) * C + (c0 + tx)];
  }
  __syncthreads();
#pragma unroll
  for (int i = 0; i < 16; ++i) {
    int cl = ty * 16 + i;
    out[(size_t)(c0 + cl) * R + (r0 + tx)] = f2bf(tile[tx][cl]);
  }
}

__global__ __launch_bounds__(256) void k_f2bf_vec(const float* __restrict__ in,
                                                  short* __restrict__ out, int n) {
  int i = blockIdx.x * 256 + threadIdx.x;
  if (i < n) out[i] = f2bf(in[i]);
}

// ---------------- gates GEMM: all 4 gates per block ----------------
// A = out_{t-1} (B x E bf16), H = h_{t-1} (B x U bf16)
// WxT: 4 x [U][E] bf16, WhT: 4 x [U][U] bf16;  part: [KSG][B][4U] f32
__global__ __launch_bounds__(128) void k_gates(const short* __restrict__ Abuf,
                                               const short* __restrict__ Hbuf,
                                               const short* __restrict__ WxT,
                                               const short* __restrict__ WhT,
                                               float* __restrict__ part, int t) {
  int gx = blockIdx.x;           // u-tile of 32: 0..31
  int z = blockIdx.y;            // 0..KSG-1
  int wave = threadIdx.x >> 6;   // 0..1
  int lane = threadIdx.x & 63;
  int l15 = lane & 15, lg = lane >> 4;
  int ucol = gx * 32 + wave * 16 + l15;

  const short* wxp[4];
  const short* whp[4];
#pragma unroll
  for (int g = 0; g < 4; ++g) {
    wxp[g] = WxT + ((size_t)g * U_ + ucol) * E_;
    whp[g] = WhT + ((size_t)g * U_ + ucol) * U_;
  }
  int c0 = (TCHUNKS * z) / KSG, c1 = (TCHUNKS * (z + 1)) / KSG;

  f32x4 zero = {};
  f32x4 acc[4][4];
#pragma unroll
  for (int g = 0; g < 4; ++g)
#pragma unroll
    for (int r = 0; r < 4; ++r) acc[g][r] = zero;

  int xe = imin(c1, XCHUNKS);
#pragma unroll 2
  for (int c = c0; c < xe; ++c) {
    int k = c * 32 + lg * 8;
    s16x8 a[4], b[4];
#pragma unroll
    for (int r = 0; r < 4; ++r)
      a[r] = *(const s16x8*)(Abuf + (size_t)(r * 16 + l15) * E_ + k);
#pragma unroll
    for (int g = 0; g < 4; ++g) b[g] = *(const s16x8*)(wxp[g] + k);
#pragma unroll
    for (int g = 0; g < 4; ++g)
#pragma unroll
      for (int r = 0; r < 4; ++r)
        acc[g][r] = __builtin_amdgcn_mfma_f32_16x16x32_bf16(a[r], b[g], acc[g][r], 0, 0, 0);
  }
  if (t > 0) {
    int h0 = imax(c0, XCHUNKS);
#pragma unroll 2
    for (int c = h0; c < c1; ++c) {
      int k = (c - XCHUNKS) * 32 + lg * 8;
      s16x8 a[4], b[4];
#pragma unroll
      for (int r = 0; r < 4; ++r)
        a[r] = *(const s16x8*)(Hbuf + (size_t)(r * 16 + l15) * U_ + k);
#pragma unroll
      for (int g = 0; g < 4; ++g) b[g] = *(const s16x8*)(whp[g] + k);
#pragma unroll
      for (int g = 0; g < 4; ++g)
#pragma unroll
        for (int r = 0; r < 4; ++r)
          acc[g][r] = __builtin_amdgcn_mfma_f32_16x16x32_bf16(a[r], b[g], acc[g][r], 0, 0, 0);
    }
  }
  // store partials (always, even for empty ranges -> zeros, since ws is poisoned)
  float* pb = part + (size_t)z * B_ * (4 * U_) + ucol;
#pragma unroll
  for (int g = 0; g < 4; ++g)
#pragma unroll
    for (int r = 0; r < 4; ++r)
#pragma unroll
      for (int j = 0; j < 4; ++j) {
        int row = r * 16 + lg * 4 + j;
        pb[(size_t)row * (4 * U_) + g * U_] = acc[g][r][j];
      }
}

// ---------------- cell update: vectorized f32x4 ----------------
__global__ __launch_bounds__(256) void k_cell(const float* __restrict__ part,
                                              const float* __restrict__ bfv,
                                              const float* __restrict__ biv,
                                              const float* __restrict__ bov,
                                              const float* __restrict__ bgv,
                                              float* __restrict__ cbuf,
                                              short* __restrict__ Hbuf, int t) {
  int idx4 = blockIdx.x * 256 + threadIdx.x;   // 0 .. B*U/4-1
  int u = (idx4 & (U_ / 4 - 1)) * 4;
  int b = idx4 >> 8;
  f32x4 pf = *(const f32x4*)(bfv + u);
  f32x4 pi = *(const f32x4*)(biv + u);
  f32x4 po = *(const f32x4*)(bov + u);
  f32x4 pg = *(const f32x4*)(bgv + u);
#pragma unroll 4
  for (int z = 0; z < KSG; ++z) {
    const float* pz = part + ((size_t)z * B_ + b) * (4 * U_) + u;
    pf += *(const f32x4*)(pz);
    pi += *(const f32x4*)(pz + U_);
    po += *(const f32x4*)(pz + 2 * U_);
    pg += *(const f32x4*)(pz + 3 * U_);
  }
  f32x4 zero = {};
  f32x4 cold = zero;
  if (t > 0) cold = *(const f32x4*)(cbuf + (size_t)b * U_ + u);
  f32x4 cn;
  s16x4 hv;
#pragma unroll
  for (int j = 0; j < 4; ++j) {
    float f = sigm(pf[j]), i = sigm(pi[j]), o = sigm(po[j]), g = sigm(pg[j]);
    float c = f * cold[j] + i * g;
    cn[j] = c;
    float th = 2.f * sigm(2.f * c) - 1.f;   // tanh(c)
    hv[j] = f2bf(th * o);
  }
  *(f32x4*)(cbuf + (size_t)b * U_ + u) = cn;
  *(s16x4*)(Hbuf + (size_t)b * U_ + u) = hv;
}

// ---------------- projection GEMM: logits partials ----------------
// H: B x U bf16, WpT: [V][U] bf16, part: [KSP][B][V] f32
__global__ __launch_bounds__(256) void k_proj(const short* __restrict__ Hbuf,
                                              const short* __restrict__ WpT,
                                              float* __restrict__ part) {
  int gx = blockIdx.x;           // v-tile of 64: 0..124
  int z = blockIdx.y;            // 0..KSP-1
  int wave = threadIdx.x >> 6;
  int lane = threadIdx.x & 63;
  int l15 = lane & 15, lg = lane >> 4;
  int vcol = gx * 64 + wave * 16 + l15;
  const short* wp = WpT + (size_t)vcol * U_;
  int c0 = (PCH * z) / KSP, c1 = (PCH * (z + 1)) / KSP;

  f32x4 zero = {};
  f32x4 acc[4];
#pragma unroll
  for (int r = 0; r < 4; ++r) acc[r] = zero;

#pragma unroll 2
  for (int c = c0; c < c1; ++c) {
    int k = c * 32 + lg * 8;
    s16x8 b = *(const s16x8*)(wp + k);
#pragma unroll
    for (int r = 0; r < 4; ++r) {
      s16x8 a = *(const s16x8*)(Hbuf + (size_t)(r * 16 + l15) * U_ + k);
      acc[r] = __builtin_amdgcn_mfma_f32_16x16x32_bf16(a, b, acc[r], 0, 0, 0);
    }
  }
  float* p = part + (size_t)z * B_ * V_ + vcol;
#pragma unroll
  for (int r = 0; r < 4; ++r)
#pragma unroll
    for (int j = 0; j < 4; ++j) {
      int row = r * 16 + lg * 4 + j;
      p[(size_t)row * V_] = acc[r][j];
    }
}

// ---------------- softmax: vectorized f32x4 ----------------
__global__ __launch_bounds__(SMT) void k_softmax(const float* __restrict__ part,
                                                 const float* __restrict__ bp,
                                                 float* __restrict__ dout,
                                                 short* __restrict__ Abuf, int t) {
  __shared__ float row[V_];
  __shared__ float red[SMT / 64 + 1];
  constexpr int NW = SMT / 64;
  constexpr int NV4 = V_ / 4;   // 2000
  int b = blockIdx.x;
  int tid = threadIdx.x, lane = tid & 63, wave = tid >> 6;
  const float* pb0 = part + (size_t)b * V_;

  float lmax = -3.4e38f;
  for (int v4 = tid; v4 < NV4; v4 += SMT) {
    int v = v4 * 4;
    f32x4 x = *(const f32x4*)(bp + v);
#pragma unroll
    for (int z = 0; z < KSP; ++z)
      x += *(const f32x4*)(pb0 + (size_t)z * B_ * V_ + v);
    *(f32x4*)(row + v) = x;
    lmax = fmaxf(fmaxf(fmaxf(lmax, x[0]), fmaxf(x[1], x[2])), x[3]);
  }
#pragma unroll
  for (int off = 32; off; off >>= 1) lmax = fmaxf(lmax, __shfl_down(lmax, off));
  if (lane == 0) red[wave] = lmax;
  __syncthreads();
  if (tid == 0) {
    float m = red[0];
    for (int w = 1; w < NW; ++w) m = fmaxf(m, red[w]);
    red[NW] = m;
  }
  __syncthreads();
  float gmax = red[NW];
  float lsum = 0.f;
  for (int v4 = tid; v4 < NV4; v4 += SMT) {
    int v = v4 * 4;
    f32x4 x = *(const f32x4*)(row + v);
    f32x4 e;
#pragma unroll
    for (int j = 0; j < 4; ++j) e[j] = __expf(x[j] - gmax);
    *(f32x4*)(row + v) = e;
    lsum += (e[0] + e[1]) + (e[2] + e[3]);
  }
#pragma unroll
  for (int off = 32; off; off >>= 1) lsum += __shfl_down(lsum, off);
  if (lane == 0) red[wave] = lsum;
  __syncthreads();
  if (tid == 0) {
    float s = 0.f;
    for (int w = 0; w < NW; ++w) s += red[w];
    red[NW] = s;
  }
  __syncthreads();
  float inv = 1.f / red[NW];
  float* po = dout + ((size_t)b * T_ + t) * V_;
  short* pa = Abuf + (size_t)b * V_;
  for (int v4 = tid; v4 < NV4; v4 += SMT) {
    int v = v4 * 4;
    f32x4 pr = *(const f32x4*)(row + v) * inv;
    *(f32x4*)(po + v) = pr;
    s16x4 pv;
#pragma unroll
    for (int j = 0; j < 4; ++j) pv[j] = f2bf(pr[j]);
    *(s16x4*)(pa + v) = pv;
  }
}

extern "C" void kernel_launch(void* const* d_in, const int* in_sizes, int n_in,
                              void* d_out, int out_size, void* d_ws, size_t ws_size,
                              hipStream_t stream) {
  const float* y = (const float*)d_in[0];
  const float* Wx[4] = {(const float*)d_in[1], (const float*)d_in[4],
                        (const float*)d_in[7], (const float*)d_in[10]};
  const float* Wh[4] = {(const float*)d_in[2], (const float*)d_in[5],
                        (const float*)d_in[8], (const float*)d_in[11]};
  const float* bs[4] = {(const float*)d_in[3], (const float*)d_in[6],
                        (const float*)d_in[9], (const float*)d_in[12]};
  const float* Wp = (const float*)d_in[13];
  const float* bp = (const float*)d_in[14];
  float* dout = (float*)d_out;

  // workspace layout (256B aligned); ~108.5 MB total
  char* w = (char*)d_ws;
  auto alloc = [&](size_t bytes) {
    char* p = w;
    w += (bytes + 255) & ~(size_t)255;
    return p;
  };
  short* WxT  = (short*)alloc((size_t)4 * U_ * E_ * 2);        // 65.5 MB
  short* WhT  = (short*)alloc((size_t)4 * U_ * U_ * 2);        // 8.4 MB
  short* WpT  = (short*)alloc((size_t)V_ * U_ * 2);            // 16.4 MB
  short* Abuf = (short*)alloc((size_t)B_ * V_ * 2);            // 1.0 MB
  short* Hbuf = (short*)alloc((size_t)B_ * U_ * 2);            // 0.13 MB
  float* cbuf = (float*)alloc((size_t)B_ * U_ * 4);            // 0.26 MB
  // partg (16.8 MB) and partp (8.2 MB) have disjoint liveness under stream
  // order (gates->cell consumes partg before proj writes partp) -> aliased.
  float* partg = (float*)alloc((size_t)KSG * B_ * 4 * U_ * 4); // 16.8 MB
  float* partp = partg;
  (void)in_sizes; (void)n_in; (void)out_size; (void)ws_size; (void)y;

  for (int g = 0; g < 4; ++g) {
    k_transpose<<<dim3(E_ / 64, U_ / 64), 256, 0, stream>>>(
        Wx[g], WxT + (size_t)g * U_ * E_, E_, U_);
    k_transpose<<<dim3(U_ / 64, U_ / 64), 256, 0, stream>>>(
        Wh[g], WhT + (size_t)g * U_ * U_, U_, U_);
  }
  k_transpose<<<dim3(U_ / 64, V_ / 64), 256, 0, stream>>>(Wp, WpT, U_, V_);
  k_f2bf_vec<<<dim3((B_ * E_ + 255) / 256), 256, 0, stream>>>(y, Abuf, B_ * E_);

  for (int t = 0; t < T_; ++t) {
    k_gates<<<dim3(32, KSG), 128, 0, stream>>>(Abuf, Hbuf, WxT, WhT, partg, t);
    k_cell<<<dim3(B_ * U_ / 1024), 256, 0, stream>>>(partg, bs[0], bs[1], bs[2],
                                                     bs[3], cbuf, Hbuf, t);
    k_proj<<<dim3(V_ / 64, KSP), 256, 0, stream>>>(Hbuf, WpT, partp);
    k_softmax<<<dim3(B_), SMT, 0, stream>>>(partp, bp, dout, Abuf, t);
  }
}

// Round 6
// 3362.748 us; speedup vs baseline: 1.3343x; 1.0109x over previous
//
#include <hip/hip_runtime.h>
#include <hip/hip_bf16.h>

// DecoderLSTM: B=64, U=1024, V=E=8000, T=64.
// bf16 MFMA GEMMs, weights pre-transposed to [N][K] once per launch.
// R5: k_gates in-block K-split (4 waves x quarter-slice) + LDS reduce.
// R6: same treatment for k_proj (KSP eliminated -> direct logits, simpler softmax).

typedef short  s16x8 __attribute__((ext_vector_type(8)));
typedef short  s16x4 __attribute__((ext_vector_type(4)));
typedef float  f32x4 __attribute__((ext_vector_type(4)));

constexpr int B_ = 64;
constexpr int U_ = 1024;
constexpr int E_ = 8000;
constexpr int V_ = 8000;
constexpr int T_ = 64;

constexpr int XCHUNKS = E_ / 32;              // 250
constexpr int HCHUNKS = U_ / 32;              // 32
constexpr int TCHUNKS = XCHUNKS + HCHUNKS;    // 282
constexpr int KSG = 16;                       // gates K-split -> 64x16=1024 blocks
constexpr int PCH = U_ / 32;                  // 32 chunks in proj K
constexpr int SMT = 1024;                     // softmax threads/block

#define DEVINL static __device__ __forceinline__

DEVINL short f2bf(float x) {
  unsigned u = __builtin_bit_cast(unsigned, x);
  unsigned r = (u + 0x7fffu + ((u >> 16) & 1u)) >> 16;   // RNE
  return (short)r;
}
DEVINL float sigm(float x) { return 1.f / (1.f + __expf(-x)); }
DEVINL int imin(int a, int b) { return a < b ? a : b; }
DEVINL int imax(int a, int b) { return a > b ? a : b; }

// ---------------- one-time weight transpose + f32->bf16 convert ----------------
__global__ __launch_bounds__(256) void k_transpose(const float* __restrict__ in,
                                                   short* __restrict__ out,
                                                   int R, int C) {
  __shared__ float tile[64][65];
  int r0 = blockIdx.x * 64, c0 = blockIdx.y * 64;
  int tx = threadIdx.x & 63, ty = threadIdx.x >> 6;
#pragma unroll
  for (int i = 0; i < 16; ++i) {
    int rl = ty * 16 + i;
    tile[rl][tx] = in[(size_t)(r0 + rl) * C + (c0 + tx)];
  }
  __syncthreads();
#pragma unroll
  for (int i = 0; i < 16; ++i) {
    int cl = ty * 16 + i;
    out[(size_t)(c0 + cl) * R + (r0 + tx)] = f2bf(tile[tx][cl]);
  }
}

__global__ __launch_bounds__(256) void k_f2bf_vec(const float* __restrict__ in,
                                                  short* __restrict__ out, int n) {
  int i = blockIdx.x * 256 + threadIdx.x;
  if (i < n) out[i] = f2bf(in[i]);
}

// ---------------- gates GEMM: 4 gates, in-block K-split, LDS reduce ----------------
// A = out_{t-1} (B x E bf16), H = h_{t-1} (B x U bf16)
// WxT: 4 x [U][E] bf16, WhT: 4 x [U][U] bf16;  part: [KSG][B][4U] f32
__global__ __launch_bounds__(256) void k_gates(const short* __restrict__ Abuf,
                                               const short* __restrict__ Hbuf,
                                               const short* __restrict__ WxT,
                                               const short* __restrict__ WhT,
                                               float* __restrict__ part, int t) {
  __shared__ float lred[2][64][64];   // 32 KB: [slot][val][lane] (lane-contig: no conflicts)
  int gx = blockIdx.x;           // u16-group: 0..63
  int z = blockIdx.y;            // 0..KSG-1
  int wave = threadIdx.x >> 6;   // 0..3 (each takes 1/4 of the K-slice)
  int lane = threadIdx.x & 63;
  int l15 = lane & 15, lg = lane >> 4;
  int ucol = gx * 16 + l15;

  const short* wxp[4];
  const short* whp[4];
#pragma unroll
  for (int g = 0; g < 4; ++g) {
    wxp[g] = WxT + ((size_t)g * U_ + ucol) * E_;
    whp[g] = WhT + ((size_t)g * U_ + ucol) * U_;
  }
  int c0 = (TCHUNKS * z) / KSG, c1 = (TCHUNKS * (z + 1)) / KSG;
  int n = c1 - c0;
  int w0 = c0 + (n * wave) / 4, w1 = c0 + (n * (wave + 1)) / 4;

  f32x4 zero = {};
  f32x4 acc[4][4];
#pragma unroll
  for (int g = 0; g < 4; ++g)
#pragma unroll
    for (int r = 0; r < 4; ++r) acc[g][r] = zero;

  int xe = imin(w1, XCHUNKS);
#pragma unroll 2
  for (int c = w0; c < xe; ++c) {
    int k = c * 32 + lg * 8;
    s16x8 a[4], b[4];
#pragma unroll
    for (int r = 0; r < 4; ++r)
      a[r] = *(const s16x8*)(Abuf + (size_t)(r * 16 + l15) * E_ + k);
#pragma unroll
    for (int g = 0; g < 4; ++g) b[g] = *(const s16x8*)(wxp[g] + k);
#pragma unroll
    for (int g = 0; g < 4; ++g)
#pragma unroll
      for (int r = 0; r < 4; ++r)
        acc[g][r] = __builtin_amdgcn_mfma_f32_16x16x32_bf16(a[r], b[g], acc[g][r], 0, 0, 0);
  }
  if (t > 0) {
    int h0 = imax(w0, XCHUNKS);
#pragma unroll 2
    for (int c = h0; c < w1; ++c) {
      int k = (c - XCHUNKS) * 32 + lg * 8;
      s16x8 a[4], b[4];
#pragma unroll
      for (int r = 0; r < 4; ++r)
        a[r] = *(const s16x8*)(Hbuf + (size_t)(r * 16 + l15) * U_ + k);
#pragma unroll
      for (int g = 0; g < 4; ++g) b[g] = *(const s16x8*)(whp[g] + k);
#pragma unroll
      for (int g = 0; g < 4; ++g)
#pragma unroll
        for (int r = 0; r < 4; ++r)
          acc[g][r] = __builtin_amdgcn_mfma_f32_16x16x32_bf16(a[r], b[g], acc[g][r], 0, 0, 0);
    }
  }

  // cross-wave tree reduce in LDS: w1->slot0, w3->slot1; w0+=s0, w2+=s1; w2->s0; w0+=s0.
  if (wave == 1 || wave == 3) {
    int slot = wave >> 1;
#pragma unroll
    for (int g = 0; g < 4; ++g)
#pragma unroll
      for (int r = 0; r < 4; ++r)
#pragma unroll
        for (int j = 0; j < 4; ++j)
          lred[slot][(g * 4 + r) * 4 + j][lane] = acc[g][r][j];
  }
  __syncthreads();
  if (wave == 0 || wave == 2) {
    int slot = wave >> 1;
#pragma unroll
    for (int g = 0; g < 4; ++g)
#pragma unroll
      for (int r = 0; r < 4; ++r)
#pragma unroll
        for (int j = 0; j < 4; ++j)
          acc[g][r][j] += lred[slot][(g * 4 + r) * 4 + j][lane];
  }
  __syncthreads();
  if (wave == 2) {
#pragma unroll
    for (int g = 0; g < 4; ++g)
#pragma unroll
      for (int r = 0; r < 4; ++r)
#pragma unroll
        for (int j = 0; j < 4; ++j)
          lred[0][(g * 4 + r) * 4 + j][lane] = acc[g][r][j];
  }
  __syncthreads();
  if (wave == 0) {
#pragma unroll
    for (int g = 0; g < 4; ++g)
#pragma unroll
      for (int r = 0; r < 4; ++r)
#pragma unroll
        for (int j = 0; j < 4; ++j)
          acc[g][r][j] += lred[0][(g * 4 + r) * 4 + j][lane];
    float* pb = part + (size_t)z * B_ * (4 * U_) + ucol;
#pragma unroll
    for (int g = 0; g < 4; ++g)
#pragma unroll
      for (int r = 0; r < 4; ++r)
#pragma unroll
        for (int j = 0; j < 4; ++j) {
          int row = r * 16 + lg * 4 + j;
          pb[(size_t)row * (4 * U_) + g * U_] = acc[g][r][j];
        }
  }
}

// ---------------- cell update: vectorized f32x4 ----------------
__global__ __launch_bounds__(256) void k_cell(const float* __restrict__ part,
                                              const float* __restrict__ bfv,
                                              const float* __restrict__ biv,
                                              const float* __restrict__ bov,
                                              const float* __restrict__ bgv,
                                              float* __restrict__ cbuf,
                                              short* __restrict__ Hbuf, int t) {
  int idx4 = blockIdx.x * 256 + threadIdx.x;   // 0 .. B*U/4-1
  int u = (idx4 & (U_ / 4 - 1)) * 4;
  int b = idx4 >> 8;
  f32x4 pf = *(const f32x4*)(bfv + u);
  f32x4 pi = *(const f32x4*)(biv + u);
  f32x4 po = *(const f32x4*)(bov + u);
  f32x4 pg = *(const f32x4*)(bgv + u);
#pragma unroll 4
  for (int z = 0; z < KSG; ++z) {
    const float* pz = part + ((size_t)z * B_ + b) * (4 * U_) + u;
    pf += *(const f32x4*)(pz);
    pi += *(const f32x4*)(pz + U_);
    po += *(const f32x4*)(pz + 2 * U_);
    pg += *(const f32x4*)(pz + 3 * U_);
  }
  f32x4 zero = {};
  f32x4 cold = zero;
  if (t > 0) cold = *(const f32x4*)(cbuf + (size_t)b * U_ + u);
  f32x4 cn;
  s16x4 hv;
#pragma unroll
  for (int j = 0; j < 4; ++j) {
    float f = sigm(pf[j]), i = sigm(pi[j]), o = sigm(po[j]), g = sigm(pg[j]);
    float c = f * cold[j] + i * g;
    cn[j] = c;
    float th = 2.f * sigm(2.f * c) - 1.f;   // tanh(c)
    hv[j] = f2bf(th * o);
  }
  *(f32x4*)(cbuf + (size_t)b * U_ + u) = cn;
  *(s16x4*)(Hbuf + (size_t)b * U_ + u) = hv;
}

// ---------------- projection GEMM: in-block K-split, direct logits ----------------
// H: B x U bf16, WpT: [V][U] bf16, logits: [B][V] f32 (final, no partials)
__global__ __launch_bounds__(256) void k_proj(const short* __restrict__ Hbuf,
                                              const short* __restrict__ WpT,
                                              float* __restrict__ logits) {
  __shared__ float lred[2][16][64];   // 8 KB
  int gx = blockIdx.x;           // v16-group: 0..499
  int wave = threadIdx.x >> 6;   // 0..3, each takes 1/4 of the 32 K-chunks
  int lane = threadIdx.x & 63;
  int l15 = lane & 15, lg = lane >> 4;
  int vcol = gx * 16 + l15;
  const short* wp = WpT + (size_t)vcol * U_;
  int w0 = (PCH * wave) / 4, w1 = (PCH * (wave + 1)) / 4;   // 8 chunks each

  f32x4 zero = {};
  f32x4 acc[4];
#pragma unroll
  for (int r = 0; r < 4; ++r) acc[r] = zero;

#pragma unroll 2
  for (int c = w0; c < w1; ++c) {
    int k = c * 32 + lg * 8;
    s16x8 b = *(const s16x8*)(wp + k);
#pragma unroll
    for (int r = 0; r < 4; ++r) {
      s16x8 a = *(const s16x8*)(Hbuf + (size_t)(r * 16 + l15) * U_ + k);
      acc[r] = __builtin_amdgcn_mfma_f32_16x16x32_bf16(a, b, acc[r], 0, 0, 0);
    }
  }

  if (wave == 1 || wave == 3) {
    int slot = wave >> 1;
#pragma unroll
    for (int r = 0; r < 4; ++r)
#pragma unroll
      for (int j = 0; j < 4; ++j)
        lred[slot][r * 4 + j][lane] = acc[r][j];
  }
  __syncthreads();
  if (wave == 0 || wave == 2) {
    int slot = wave >> 1;
#pragma unroll
    for (int r = 0; r < 4; ++r)
#pragma unroll
      for (int j = 0; j < 4; ++j)
        acc[r][j] += lred[slot][r * 4 + j][lane];
  }
  __syncthreads();
  if (wave == 2) {
#pragma unroll
    for (int r = 0; r < 4; ++r)
#pragma unroll
      for (int j = 0; j < 4; ++j)
        lred[0][r * 4 + j][lane] = acc[r][j];
  }
  __syncthreads();
  if (wave == 0) {
#pragma unroll
    for (int r = 0; r < 4; ++r)
#pragma unroll
      for (int j = 0; j < 4; ++j) {
        int row = r * 16 + lg * 4 + j;
        logits[(size_t)row * V_ + vcol] = acc[r][j] + lred[0][r * 4 + j][lane];
      }
  }
}

// ---------------- softmax: single logits read, vectorized f32x4 ----------------
__global__ __launch_bounds__(SMT) void k_softmax(const float* __restrict__ logits,
                                                 const float* __restrict__ bp,
                                                 float* __restrict__ dout,
                                                 short* __restrict__ Abuf, int t) {
  __shared__ float row[V_];
  __shared__ float red[SMT / 64 + 1];
  constexpr int NW = SMT / 64;
  constexpr int NV4 = V_ / 4;   // 2000
  int b = blockIdx.x;
  int tid = threadIdx.x, lane = tid & 63, wave = tid >> 6;
  const float* pb0 = logits + (size_t)b * V_;

  float lmax = -3.4e38f;
  for (int v4 = tid; v4 < NV4; v4 += SMT) {
    int v = v4 * 4;
    f32x4 x = *(const f32x4*)(bp + v) + *(const f32x4*)(pb0 + v);
    *(f32x4*)(row + v) = x;
    lmax = fmaxf(fmaxf(fmaxf(lmax, x[0]), fmaxf(x[1], x[2])), x[3]);
  }
#pragma unroll
  for (int off = 32; off; off >>= 1) lmax = fmaxf(lmax, __shfl_down(lmax, off));
  if (lane == 0) red[wave] = lmax;
  __syncthreads();
  if (tid == 0) {
    float m = red[0];
    for (int w = 1; w < NW; ++w) m = fmaxf(m, red[w]);
    red[NW] = m;
  }
  __syncthreads();
  float gmax = red[NW];
  float lsum = 0.f;
  for (int v4 = tid; v4 < NV4; v4 += SMT) {
    int v = v4 * 4;
    f32x4 x = *(const f32x4*)(row + v);
    f32x4 e;
#pragma unroll
    for (int j = 0; j < 4; ++j) e[j] = __expf(x[j] - gmax);
    *(f32x4*)(row + v) = e;
    lsum += (e[0] + e[1]) + (e[2] + e[3]);
  }
#pragma unroll
  for (int off = 32; off; off >>= 1) lsum += __shfl_down(lsum, off);
  if (lane == 0) red[wave] = lsum;
  __syncthreads();
  if (tid == 0) {
    float s = 0.f;
    for (int w = 0; w < NW; ++w) s += red[w];
    red[NW] = s;
  }
  __syncthreads();
  float inv = 1.f / red[NW];
  float* po = dout + ((size_t)b * T_ + t) * V_;
  short* pa = Abuf + (size_t)b * V_;
  for (int v4 = tid; v4 < NV4; v4 += SMT) {
    int v = v4 * 4;
    f32x4 pr = *(const f32x4*)(row + v) * inv;
    *(f32x4*)(po + v) = pr;
    s16x4 pv;
#pragma unroll
    for (int j = 0; j < 4; ++j) pv[j] = f2bf(pr[j]);
    *(s16x4*)(pa + v) = pv;
  }
}

extern "C" void kernel_launch(void* const* d_in, const int* in_sizes, int n_in,
                              void* d_out, int out_size, void* d_ws, size_t ws_size,
                              hipStream_t stream) {
  const float* y = (const float*)d_in[0];
  const float* Wx[4] = {(const float*)d_in[1], (const float*)d_in[4],
                        (const float*)d_in[7], (const float*)d_in[10]};
  const float* Wh[4] = {(const float*)d_in[2], (const float*)d_in[5],
                        (const float*)d_in[8], (const float*)d_in[11]};
  const float* bs[4] = {(const float*)d_in[3], (const float*)d_in[6],
                        (const float*)d_in[9], (const float*)d_in[12]};
  const float* Wp = (const float*)d_in[13];
  const float* bp = (const float*)d_in[14];
  float* dout = (float*)d_out;

  // workspace layout (256B aligned); ~108.5 MB total
  char* w = (char*)d_ws;
  auto alloc = [&](size_t bytes) {
    char* p = w;
    w += (bytes + 255) & ~(size_t)255;
    return p;
  };
  short* WxT  = (short*)alloc((size_t)4 * U_ * E_ * 2);        // 65.5 MB
  short* WhT  = (short*)alloc((size_t)4 * U_ * U_ * 2);        // 8.4 MB
  short* WpT  = (short*)alloc((size_t)V_ * U_ * 2);            // 16.4 MB
  short* Abuf = (short*)alloc((size_t)B_ * V_ * 2);            // 1.0 MB
  short* Hbuf = (short*)alloc((size_t)B_ * U_ * 2);            // 0.13 MB
  float* cbuf = (float*)alloc((size_t)B_ * U_ * 4);            // 0.26 MB
  // partg (16.8 MB, gates partials) and logits (2 MB) have disjoint liveness
  // under stream order -> aliased into the same region.
  float* partg = (float*)alloc((size_t)KSG * B_ * 4 * U_ * 4); // 16.8 MB
  float* logits = partg;
  (void)in_sizes; (void)n_in; (void)out_size; (void)ws_size;

  for (int g = 0; g < 4; ++g) {
    k_transpose<<<dim3(E_ / 64, U_ / 64), 256, 0, stream>>>(
        Wx[g], WxT + (size_t)g * U_ * E_, E_, U_);
    k_transpose<<<dim3(U_ / 64, U_ / 64), 256, 0, stream>>>(
        Wh[g], WhT + (size_t)g * U_ * U_, U_, U_);
  }
  k_transpose<<<dim3(U_ / 64, V_ / 64), 256, 0, stream>>>(Wp, WpT, U_, V_);
  k_f2bf_vec<<<dim3((B_ * E_ + 255) / 256), 256, 0, stream>>>(y, Abuf, B_ * E_);

  for (int t = 0; t < T_; ++t) {
    k_gates<<<dim3(64, KSG), 256, 0, stream>>>(Abuf, Hbuf, WxT, WhT, partg, t);
    k_cell<<<dim3(B_ * U_ / 1024), 256, 0, stream>>>(partg, bs[0], bs[1], bs[2],
                                                     bs[3], cbuf, Hbuf, t);
    k_proj<<<dim3(500), 256, 0, stream>>>(Hbuf, WpT, logits);
    k_softmax<<<dim3(B_), SMT, 0, stream>>>(logits, bp, dout, Abuf, t);
  }
}